// Round 12
// baseline (353.156 us; speedup 1.0000x reference)
//
#include <hip/hip_runtime.h>

// GAT 3-layer (N=50000, E=800000 (+N self loops), H=2, C=64, widths 128)
// Round 12: fused_agg reverted to R10 register-prefetch form (R11 LDS staging
// regressed: 200k bank conflicts + gather addresses serialized behind ds_read;
// R7/R10 show ~46us is the gather-service floor). gemm rewritten with
// coalesced LDS-staged A tile (BN+ReLU+bf16 convert in flight, padded rows,
// ds_read_b128 fragments). scatter_pos XCD-partitioned by dst range
// (atomic-free via rank) to keep csr writes XCD-local.

#define N_NODES 50000
#define N_EDGES 800000
#define ET (N_EDGES + N_NODES)   // 850000 incl self loops
#define FDIM 128
#define SLOPE 0.2f
#define BN_EPS 1e-5f
#define SCAN_NB 196              // ceil(50000/256)
#define LOG2E 1.44269504088896340736f
#define WSTRIDE 18432            // 9 tiles * 4 ks * 64 lanes * 8
#define NRANGE 8
#define RNODES (N_NODES / NRANGE)          // 6250
#define SCAT_SUB 96
#define SCAT_CH ((ET + SCAT_SUB - 1) / SCAT_SUB)   // 8855

typedef __attribute__((ext_vector_type(8))) short bf16x8;
typedef __attribute__((ext_vector_type(4))) float f32x4;
typedef __attribute__((ext_vector_type(8))) unsigned short u16x8;

__device__ __forceinline__ unsigned short f2bf(float f) {
  unsigned u = __float_as_uint(f);
  u = u + 0x7fffu + ((u >> 16) & 1u);   // RNE
  return (unsigned short)(u >> 16);
}
__device__ __forceinline__ unsigned packbf(float lo, float hi) {
  return ((unsigned)f2bf(hi) << 16) | (unsigned)f2bf(lo);
}
__device__ __forceinline__ float bflo(unsigned p) { return __uint_as_float(p << 16); }
__device__ __forceinline__ float bfhi(unsigned p) { return __uint_as_float(p & 0xffff0000u); }

// ---------------- CSR build (rank-based) ----------------

__global__ __launch_bounds__(256) void hist_rank(const int* __restrict__ dst,
                                                 int* __restrict__ counts,
                                                 int* __restrict__ rank) {
  int i = blockIdx.x * 256 + threadIdx.x;
  if (i >= ET) return;
  int d = (i < N_EDGES) ? dst[i] : i - N_EDGES;
  rank[i] = atomicAdd(&counts[d], 1);
}

__global__ __launch_bounds__(256) void scan_blk(const int* __restrict__ counts,
                                                int* __restrict__ rowptr,
                                                int* __restrict__ partials) {
  int i = blockIdx.x * 256 + threadIdx.x;
  int lane = threadIdx.x & 63, wv = threadIdx.x >> 6;
  int c = (i < N_NODES) ? counts[i] : 0;
  int v = c;
#pragma unroll
  for (int off = 1; off < 64; off <<= 1) {
    int u = __shfl_up(v, off);
    if (lane >= off) v += u;
  }
  __shared__ int wsum[4];
  if (lane == 63) wsum[wv] = v;
  __syncthreads();
  int add = 0;
  for (int w = 0; w < wv; ++w) add += wsum[w];
  if (i < N_NODES) rowptr[i] = v - c + add;
  if (threadIdx.x == 255) partials[blockIdx.x] = add + v;
}

// final pass: each block reduces partials[0..blockIdx) inline (196 values)
__global__ __launch_bounds__(256) void scan_fin(int* __restrict__ rowptr,
                                                const int* __restrict__ partials) {
  __shared__ int sh[256];
  int t = threadIdx.x;
  sh[t] = (t < (int)blockIdx.x && t < SCAN_NB) ? partials[t] : 0;
  __syncthreads();
#pragma unroll
  for (int off = 128; off > 0; off >>= 1) {
    if (t < off) sh[t] += sh[t + off];
    __syncthreads();
  }
  int base = sh[0];
  int i = blockIdx.x * 256 + t;
  if (i < N_NODES) rowptr[i] += base;
  if (i == 0) rowptr[N_NODES] = ET;
}

// XCD-partitioned, atomic-free scatter: range = blockIdx&7 keeps the random
// csr_src writes local to one XCD's L2 (single writeback instead of
// cross-XCD line bouncing).
__global__ __launch_bounds__(256) void scatter_pos(const int* __restrict__ src,
                                                   const int* __restrict__ dst,
                                                   const int* __restrict__ rowptr,
                                                   const int* __restrict__ rank,
                                                   int* __restrict__ csr_src) {
  int r = blockIdx.x & (NRANGE - 1);
  int s = blockIdx.x >> 3;
  int lo = r * RNODES, hi = lo + RNODES;
  int e0 = s * SCAT_CH;
  int e1 = e0 + SCAT_CH; if (e1 > ET) e1 = ET;
  for (int i = e0 + threadIdx.x; i < e1; i += 256) {
    int d = (i < N_EDGES) ? dst[i] : i - N_EDGES;
    if (d >= lo && d < hi) {
      int sv = (i < N_EDGES) ? src[i] : d;
      csr_src[rowptr[d] + rank[i]] = sv;
    }
  }
}

// ---------------- W repack: B-fragment order + 4 logit columns (tile 8) ----
__global__ __launch_bounds__(256) void repack_w(const float* __restrict__ W0,
                                                const float* __restrict__ W1,
                                                const float* __restrict__ W2,
                                                const float* __restrict__ as0,
                                                const float* __restrict__ as1,
                                                const float* __restrict__ as2,
                                                const float* __restrict__ ad0,
                                                const float* __restrict__ ad1,
                                                const float* __restrict__ ad2,
                                                unsigned short* __restrict__ Wr) {
  int i = blockIdx.x * 256 + threadIdx.x;
  if (i >= 3 * WSTRIDE) return;
  int L = i / WSTRIDE, rem = i % WSTRIDE;
  int t  = rem >> 11;
  int ks = (rem >> 9) & 3;
  int ln = (rem >> 3) & 63;
  int j  = rem & 7;
  int k  = ks * 32 + (ln >> 4) * 8 + j;
  const float* W = (L == 0) ? W0 : ((L == 1) ? W1 : W2);
  float val;
  if (t < 8) {
    int col = t * 16 + (ln & 15);
    val = W[k * 128 + col];
  } else {
    int cl = ln & 15;
    if (cl < 4) {
      int head = cl & 1;
      const float* a = (cl < 2) ? ((L == 0) ? as0 : (L == 1) ? as1 : as2)
                                : ((L == 0) ? ad0 : (L == 1) ? ad1 : ad2);
      float s = 0.f;
      const float* wrow = W + k * 128 + head * 64;
      const float* ah = a + head * 64;
#pragma unroll 8
      for (int c = 0; c < 64; ++c) s = fmaf(wrow[c], ah[c], s);
      val = s * LOG2E;
    } else {
      val = 0.f;
    }
  }
  Wr[i] = f2bf(val);
}

// ---------------- BN finalize: part[32][256] -> lsbuf[256] (scale|shift) ----
__global__ __launch_bounds__(128) void bn_fin(const float* __restrict__ part,
                                              const float* __restrict__ g,
                                              const float* __restrict__ be,
                                              float* __restrict__ lsbuf) {
  int t = threadIdx.x;   // 0..127
  float s = 0.f, q = 0.f;
#pragma unroll
  for (int k = 0; k < 32; ++k) {
    s += part[k * 256 + t];
    q += part[k * 256 + 128 + t];
  }
  float mu  = s * (1.f / N_NODES);
  float var = q * (1.f / N_NODES) - mu * mu;
  float sc  = rsqrtf(var + BN_EPS) * g[t];
  lsbuf[t]       = sc;
  lsbuf[128 + t] = be[t] - mu * sc;
}

// ---------------- MFMA gemm, LDS-staged A tile ------------------------------
// Block = 256 thr = 4 waves x 16 rows (64 rows/block). Stage: coalesced
// global loads (4 threads/row), BN+ReLU+bf16 convert in flight, into padded
// LDS tile xt[64][136] (row stride 272B -> 2-way banks = free). Waves
// ds_read_b128 A fragments. 9 B tiles (8 H cols + logit cols from repack_w).
// Transpose buffer reuses xt (barrier-separated).
__global__ __launch_bounds__(256) void gemm_mfma(const void* __restrict__ Xin,
                                                 const unsigned short* __restrict__ WrL,
                                                 const float* __restrict__ lsbuf,
                                                 unsigned short* __restrict__ Hbf,
                                                 float* __restrict__ als,
                                                 float* __restrict__ ald,
                                                 int inBF) {
  __shared__ unsigned short xt[64][136];     // 17.4 KB, also reused as transpose buf
  __shared__ float ls_scale[128], ls_shift[128];
  int tid = threadIdx.x;
  int row0 = blockIdx.x * 64;

  if (inBF) {
    if (tid < 128) {
      ls_scale[tid] = lsbuf[tid];
      ls_shift[tid] = lsbuf[128 + tid];
    }
    __syncthreads();
  }

  // ---- stage A tile (coalesced) ----
  {
    int r = tid >> 2;          // 0..63 local row
    int q = tid & 3;           // quarter: channels [q*32, q*32+32)
    int row = row0 + r;
    int rc = row < N_NODES ? row : N_NODES - 1;
    unsigned* xr = (unsigned*)&xt[0][0] + r * 68;   // row base in u32 (136 u16)
    if (inBF) {
      const uint4* p = (const uint4*)((const unsigned*)Xin + (size_t)rc * 64 + q * 16);
#pragma unroll
      for (int b = 0; b < 4; ++b) {
        uint4 v = p[b];
        unsigned wbase = q * 16 + b * 4;   // u32 word index in row
        unsigned wv[4] = {v.x, v.y, v.z, v.w};
#pragma unroll
        for (int k = 0; k < 4; ++k) {
          int c = (wbase + k) * 2;
          float f0 = fmaf(bflo(wv[k]), ls_scale[c],     ls_shift[c]);
          float f1 = fmaf(bfhi(wv[k]), ls_scale[c + 1], ls_shift[c + 1]);
          f0 = f0 > 0.f ? f0 : 0.f;
          f1 = f1 > 0.f ? f1 : 0.f;
          xr[wbase + k] = packbf(f0, f1);
        }
      }
    } else {
      const float4* p = (const float4*)((const float*)Xin + (size_t)rc * FDIM + q * 32);
#pragma unroll
      for (int b = 0; b < 8; ++b) {
        float4 v = p[b];
        int w = q * 16 + b * 2;
        xr[w]     = packbf(v.x, v.y);
        xr[w + 1] = packbf(v.z, v.w);
      }
    }
  }
  __syncthreads();

  // ---- MFMA loop ----
  int lane = tid & 63;
  int wv   = tid >> 6;
  int gidx = lane & 15;
  int quad = lane >> 4;
  f32x4 acc[9] = {};
#pragma unroll
  for (int ks = 0; ks < 4; ++ks) {
    bf16x8 afrag = *(const bf16x8*)&xt[wv * 16 + gidx][ks * 32 + quad * 8];
#pragma unroll
    for (int t = 0; t < 9; ++t) {
      bf16x8 bfrag = *(const bf16x8*)(WrL + ((size_t)((t * 4 + ks) * 64 + lane)) * 8);
      acc[t] = __builtin_amdgcn_mfma_f32_16x16x32_bf16(afrag, bfrag, acc[t], 0, 0, 0);
    }
  }

  // ---- logit columns: lane (quad,gidx<4) holds al[row=quad*4+r][gidx] ----
  int wrow0 = row0 + wv * 16;
  if (gidx < 4) {
    float* dp = (gidx < 2) ? als : ald;
    int hd = gidx & 1;
#pragma unroll
    for (int r = 0; r < 4; ++r) {
      int row = wrow0 + quad * 4 + r;
      if (row < N_NODES) dp[row * 2 + hd] = acc[8][r];
    }
  }

  // ---- bf16 H store via LDS transpose (reuse xt memory) ----
  __syncthreads();   // all waves done reading xt
  unsigned short* tr = &xt[0][0];   // [4][16][128]
#pragma unroll
  for (int t = 0; t < 8; ++t)
#pragma unroll
    for (int r = 0; r < 4; ++r)
      tr[wv * 2048 + (quad * 4 + r) * 128 + t * 16 + gidx] = f2bf(acc[t][r]);
  __syncthreads();
#pragma unroll
  for (int it = 0; it < 4; ++it) {
    int rloc = it * 4 + quad;
    int row = wrow0 + rloc;
    if (row < N_NODES)
      *(u16x8*)(Hbf + (size_t)row * FDIM + gidx * 8) =
          *(u16x8*)&tr[wv * 2048 + rloc * 128 + gidx * 8];
  }
}

// ---------------- fused softmax-aggregate (R10 register version) -----------
// One wave per node. Lane owns channels 2l,2l+1; lanes 0-31 = head 0,
// 32-63 = head 1. Logits are log2-scaled -> exp2f. No max shift.
// 8-deep clamped register prefetch. mode 0: write Abf bf16-pair + BN sums;
// mode 2: head-mean + b2 -> out fp32 [N,64].
__global__ __launch_bounds__(256) void fused_agg(const int* __restrict__ rowptr,
                                                 const int* __restrict__ csr_src,
                                                 const unsigned* __restrict__ H2,
                                                 const float* __restrict__ als,
                                                 const float* __restrict__ ald,
                                                 unsigned* __restrict__ Abf,
                                                 float* __restrict__ out,
                                                 const float* __restrict__ b2,
                                                 float* __restrict__ part,
                                                 int mode) {
  int lane = threadIdx.x & 63;
  bool hi = lane >= 32;
  int n = __builtin_amdgcn_readfirstlane((blockIdx.x * 256 + threadIdx.x) >> 6);
  int beg = rowptr[n], end = rowptr[n + 1];
  float2 adv = ((const float2*)ald)[n];
  float advh = hi ? adv.y : adv.x;

  int b0 = end - 8; if (b0 > beg) b0 = beg; if (b0 < 0) b0 = 0;
  int delta = beg - b0;
  int sa[8]; float2 aa[8]; unsigned ha[8];
#pragma unroll
  for (int i = 0; i < 8; ++i) sa[i] = csr_src[b0 + i];
#pragma unroll
  for (int i = 0; i < 8; ++i) {
    aa[i] = ((const float2*)als)[sa[i]];
    ha[i] = H2[(size_t)sa[i] * 64 + lane];
  }

  float l = 0.f, ox = 0.f, oy = 0.f;

#define STEP(i) { \
    float v_ = (hi ? aa[i].y : aa[i].x) + advh; \
    v_ = fmaxf(v_, SLOPE * v_); \
    float e_ = exp2f(v_); \
    l += e_; \
    ox = fmaf(e_, bflo(ha[i]), ox); \
    oy = fmaf(e_, bfhi(ha[i]), oy); }

  int j = beg;
  for (; j + 8 <= end; j += 8) {
    int pp = j + 8; if (pp > end - 8) pp = end - 8;   // end-8 >= beg here
    int sn[8]; float2 an[8]; unsigned hn[8];
#pragma unroll
    for (int i = 0; i < 8; ++i) sn[i] = csr_src[pp + i];
#pragma unroll
    for (int i = 0; i < 8; ++i) {
      an[i] = ((const float2*)als)[sn[i]];
      hn[i] = H2[(size_t)sn[i] * 64 + lane];
    }
    STEP(0); STEP(1); STEP(2); STEP(3); STEP(4); STEP(5); STEP(6); STEP(7);
    delta = j + 8 - pp;
#pragma unroll
    for (int i = 0; i < 8; ++i) { aa[i] = an[i]; ha[i] = hn[i]; }
  }
  int rem = end - j;
  int hik = delta + rem;
  if (0 >= delta && 0 < hik) STEP(0);
  if (1 >= delta && 1 < hik) STEP(1);
  if (2 >= delta && 2 < hik) STEP(2);
  if (3 >= delta && 3 < hik) STEP(3);
  if (4 >= delta && 4 < hik) STEP(4);
  if (5 >= delta && 5 < hik) STEP(5);
  if (6 >= delta && 6 < hik) STEP(6);
  if (7 >= delta && 7 < hik) STEP(7);
#undef STEP

  float inv = 1.f / (l + 1e-16f);
  ox *= inv; oy *= inv;

  if (mode == 0) {
    Abf[(size_t)n * 64 + lane] = packbf(ox, oy);
    __shared__ float sh[4][4][64];
    int wv = threadIdx.x >> 6;
    sh[wv][0][lane] = ox;
    sh[wv][1][lane] = oy;
    sh[wv][2][lane] = ox * ox;
    sh[wv][3][lane] = oy * oy;
    __syncthreads();
    if (threadIdx.x < 64) {
      int t = threadIdx.x;
      float a0 = 0.f, a1 = 0.f, a2 = 0.f, a3 = 0.f;
#pragma unroll
      for (int w = 0; w < 4; ++w) {
        a0 += sh[w][0][t]; a1 += sh[w][1][t];
        a2 += sh[w][2][t]; a3 += sh[w][3][t];
      }
      float* slot = part + (blockIdx.x & 31) * 256;
      atomicAdd(&slot[2 * t],           a0);
      atomicAdd(&slot[2 * t + 1],       a1);
      atomicAdd(&slot[128 + 2 * t],     a2);
      atomicAdd(&slot[128 + 2 * t + 1], a3);
    }
  } else {
    float px = __shfl_xor(ox, 32);
    float py = __shfl_xor(oy, 32);
    if (lane < 32) {
      int c = lane * 2;
      float2 outv = {0.5f * (ox + px) + b2[c], 0.5f * (oy + py) + b2[c + 1]};
      *(float2*)(out + (size_t)n * 64 + c) = outv;
    }
  }
}

extern "C" void kernel_launch(void* const* d_in, const int* in_sizes, int n_in,
                              void* d_out, int out_size, void* d_ws, size_t ws_size,
                              hipStream_t stream) {
  const float* x  = (const float*)d_in[0];
  const int*   ei = (const int*)d_in[1];
  const int* src = ei;
  const int* dst = ei + N_EDGES;

  const float* W[3]    = {(const float*)d_in[2],  (const float*)d_in[8],  (const float*)d_in[14]};
  const float* asrc[3] = {(const float*)d_in[3],  (const float*)d_in[9],  (const float*)d_in[15]};
  const float* adst[3] = {(const float*)d_in[4],  (const float*)d_in[10], (const float*)d_in[16]};
  const float* g[2]    = {(const float*)d_in[6],  (const float*)d_in[12]};
  const float* be[2]   = {(const float*)d_in[7],  (const float*)d_in[13]};
  const float* b2      = (const float*)d_in[17];

  // workspace (4-byte units, regions 16B-aligned):
  int*   counts   = (int*)d_ws;
  int*   rowptr   = counts + 50048;
  int*   partials = rowptr + 50048;
  int*   rank     = partials + 256;
  int*   csr_src  = rank + 850048;
  float* part     = (float*)(csr_src + 850048);  // 32*256 BN partial slots
  float* lsbuf    = part + 8192;                  // 256 scale|shift
  float* als      = lsbuf + 256;
  float* ald      = als + 100096;
  unsigned short* Wr  = (unsigned short*)(ald + 100096);   // 3*WSTRIDE u16
  unsigned short* Hbf = Wr + 3 * WSTRIDE + 128;            // pad to 16B align
  unsigned* Abf   = (unsigned*)(Hbf + (size_t)N_NODES * FDIM);

  // ---- build CSR + repack W (edge set / weights constant across layers) ----
  hipMemsetAsync(counts, 0, (size_t)N_NODES * sizeof(int), stream);
  hist_rank<<<(ET + 255) / 256, 256, 0, stream>>>(dst, counts, rank);
  scan_blk<<<SCAN_NB, 256, 0, stream>>>(counts, rowptr, partials);
  scan_fin<<<SCAN_NB, 256, 0, stream>>>(rowptr, partials);
  scatter_pos<<<NRANGE * SCAT_SUB, 256, 0, stream>>>(src, dst, rowptr, rank, csr_src);
  repack_w<<<(3 * WSTRIDE + 255) / 256, 256, 0, stream>>>(
      W[0], W[1], W[2], asrc[0], asrc[1], asrc[2], adst[0], adst[1], adst[2], Wr);

  const int gemm_grid = (N_NODES + 63) / 64;
  const int agg_grid  = N_NODES * 64 / 256;   // 12500, exact (one wave/node)

  for (int L = 0; L < 3; ++L) {
    const void* fin = (L == 0) ? (const void*)x : (const void*)Abf;
    int inBF = (L > 0);
    gemm_mfma<<<gemm_grid, 256, 0, stream>>>(fin, Wr + (size_t)L * WSTRIDE, lsbuf,
                                             Hbf, als, ald, inBF);
    if (L < 2)
      hipMemsetAsync(part, 0, 8192 * sizeof(float), stream);
    fused_agg<<<agg_grid, 256, 0, stream>>>(rowptr, csr_src, (const unsigned*)Hbf,
                                            als, ald, Abf, (float*)d_out, b2, part,
                                            (L == 2) ? 2 : 0);
    if (L < 2)
      bn_fin<<<1, 128, 0, stream>>>(part, g[L], be[L], lsbuf);
  }
}